// Round 7
// baseline (129.608 us; speedup 1.0000x reference)
//
#include <hip/hip_runtime.h>

#define MD 4
#define DD 9          // 2*MD+1
#define KK 81         // DD*DD
#define B_ 4
#define C_ 128
#define H_ 192
#define W_ 192
#define HW (H_ * W_)
#define NWG 4608      // 2 chalf * 3 xt * 192 y * 4 b
#define PER_XCD (NWG / 8)

// out[b,c,y,x] = (1/C) * sum_{p,o} first[b,p*9+o,y,x] * second[b,c,y+p-4,x+o-4]
//
// Round 7 = round-6 body + sched_barrier(0) fences pinning the software
// pipeline. History: round 4 (90.6us) pipelined only because 72-VGPR pressure
// anchored the schedule; rounds 5/6 shrank live ranges (VGPR 60/64) and the
// scheduler sank the prefetch loads into their uses (VALUBusy 39->28%,
// dur 127-134us). Fences make the load-ahead structural:
//   {ds_read fo} | {h-loads} | {FMA g} | {advance + g-loads} | {FMA h}
// Compiler emits counted vmcnt automatically (loads stay 1 FMA-block ahead).
// X-edges folded into weights at stage time (proven, absmax unchanged).
// (256,1): no VGPR pin. Spill sentinel: WRITE_SIZE must stay == 73728 KB.

#define SB() __builtin_amdgcn_sched_barrier(0)

__device__ __forceinline__ void unpack12(float (&s)[12],
                                         const float4& A, const float4& M,
                                         const float4& E) {
  s[0] = A.x; s[1] = A.y; s[2]  = A.z; s[3]  = A.w;
  s[4] = M.x; s[5] = M.y; s[6]  = M.z; s[7]  = M.w;
  s[8] = E.x; s[9] = E.y; s[10] = E.z; s[11] = E.w;
}

#define FMA_GROUP(accp, s)                                   \
  _Pragma("unroll")                                          \
  for (int o = 0; o < DD; ++o) {                             \
    accp[0] = fmaf(fo[o].x, s[o + 0], accp[0]);              \
    accp[1] = fmaf(fo[o].y, s[o + 1], accp[1]);              \
    accp[2] = fmaf(fo[o].z, s[o + 2], accp[2]);              \
    accp[3] = fmaf(fo[o].w, s[o + 3], accp[3]);              \
  }

__global__ __launch_bounds__(256, 1)
void corr_transpose_kernel(const float* __restrict__ first,
                           const float* __restrict__ second,
                           float* __restrict__ out) {
  __shared__ __align__(16) float ldsF[KK * 64];

  // bijective XCD swizzle (4608 % 8 == 0), y-fastest within an XCD chunk
  const int lin = blockIdx.x;
  const int wid = (lin & 7) * PER_XCD + (lin >> 3);
  const int y     = wid % H_;
  const int t     = wid / H_;          // 0..23
  const int chalf = t & 1;
  const int xt0   = ((t >> 1) % 3) * 64;
  const int b     = t / 6;

  const int tid = threadIdx.x;

  // ---- stage first[b,:,y,xt0..+63] into LDS with X-edge weight masking ----
  {
    const float* fbase = first + ((size_t)(b * KK) * H_ + y) * (size_t)W_ + xt0;
    const bool edge = (xt0 != 64);     // block-uniform
    for (int idx = tid; idx < KK * 16; idx += 256) {
      const int k  = idx >> 4;
      const int xi = (idx & 15) << 2;
      float4 v = *reinterpret_cast<const float4*>(fbase + (size_t)k * HW + xi);
      if (edge) {
        const int o    = k % DD;
        const int base = xt0 + xi + o - MD;   // second-x for component 0
        if (base + 0 < 0 || base + 0 >= W_) v.x = 0.f;
        if (base + 1 < 0 || base + 1 >= W_) v.y = 0.f;
        if (base + 2 < 0 || base + 2 >= W_) v.z = 0.f;
        if (base + 3 < 0 || base + 3 >= W_) v.w = 0.f;
      }
      *reinterpret_cast<float4*>(&ldsF[k * 64 + xi]) = v;
    }
  }

  const int xg = tid & 15;
  const int cg = tid >> 4;
  const int c0 = chalf * 64 + cg * 4;
  const int x0 = xt0 + xg * 4;

  // clamped per-lane offsets; OOB float4s have zeroed weights in LDS
  const bool mA = (x0 != 0);
  const bool mE = (x0 + 8 <= W_);
  const int  oa = mA ? x0 - 4 : 0;
  const int  oe = mE ? x0 + 4 : W_ - 8;

  // p-loop bounds hoisted (block-uniform)
  const int pstart = (y >= MD) ? 0 : (MD - y);
  const int pend   = (y + MD < H_) ? DD : (H_ + MD - y);
  const int yy0    = y + pstart - MD;

  const float* secB = second + (size_t)b * C_ * HW;
  const float* rp0 = secB + ((size_t)c0 * H_ + yy0) * (size_t)W_;
  const float* rp1 = rp0 + HW;
  const float* rp2 = rp1 + HW;
  const float* rp3 = rp2 + HW;

  // prologue: group-0 loads in flight while LDS staging drains
  float4 gA0 = *reinterpret_cast<const float4*>(rp0 + oa);
  float4 gM0 = *reinterpret_cast<const float4*>(rp0 + x0);
  float4 gE0 = *reinterpret_cast<const float4*>(rp0 + oe);
  float4 gA1 = *reinterpret_cast<const float4*>(rp1 + oa);
  float4 gM1 = *reinterpret_cast<const float4*>(rp1 + x0);
  float4 gE1 = *reinterpret_cast<const float4*>(rp1 + oe);

  __syncthreads();

  float acc0[4] = {0.f, 0.f, 0.f, 0.f};
  float acc1[4] = {0.f, 0.f, 0.f, 0.f};
  float acc2[4] = {0.f, 0.f, 0.f, 0.f};
  float acc3[4] = {0.f, 0.f, 0.f, 0.f};

  for (int p = pstart; p < pend; ++p) {
    // ---- phase A: LDS weight reads for this p ----
    float4 fo[DD];
#pragma unroll
    for (int o = 0; o < DD; ++o)
      fo[o] = *reinterpret_cast<const float4*>(&ldsF[(p * DD + o) * 64 + (xg << 2)]);
    SB();

    // ---- phase B: issue group-1 loads (current p) ----
    float4 hA0 = *reinterpret_cast<const float4*>(rp2 + oa);
    float4 hM0 = *reinterpret_cast<const float4*>(rp2 + x0);
    float4 hE0 = *reinterpret_cast<const float4*>(rp2 + oe);
    float4 hA1 = *reinterpret_cast<const float4*>(rp3 + oa);
    float4 hM1 = *reinterpret_cast<const float4*>(rp3 + x0);
    float4 hE1 = *reinterpret_cast<const float4*>(rp3 + oe);
    SB();

    // ---- phase C: FMA group 0 (channels c0, c0+1) ----
    {
      float s[12];
      unpack12(s, gA0, gM0, gE0);
      FMA_GROUP(acc0, s);
      float u[12];
      unpack12(u, gA1, gM1, gE1);
      FMA_GROUP(acc1, u);
    }
    SB();

    // ---- phase D: advance rows + issue group-0 loads for next p ----
    const int adv = (p + 1 < pend) ? W_ : 0;  // last iter: dead in-bounds reload
    rp0 += adv; rp1 += adv; rp2 += adv; rp3 += adv;
    gA0 = *reinterpret_cast<const float4*>(rp0 + oa);
    gM0 = *reinterpret_cast<const float4*>(rp0 + x0);
    gE0 = *reinterpret_cast<const float4*>(rp0 + oe);
    gA1 = *reinterpret_cast<const float4*>(rp1 + oa);
    gM1 = *reinterpret_cast<const float4*>(rp1 + x0);
    gE1 = *reinterpret_cast<const float4*>(rp1 + oe);
    SB();

    // ---- phase E: FMA group 1 (channels c0+2, c0+3) ----
    {
      float s[12];
      unpack12(s, hA0, hM0, hE0);
      FMA_GROUP(acc2, s);
      float u[12];
      unpack12(u, hA1, hM1, hE1);
      FMA_GROUP(acc3, u);
    }
  }

  const float inv_c = 1.0f / (float)C_;
  float* outB = out + (size_t)b * C_ * HW + (size_t)y * W_ + x0;
  {
    float4 v;
    v.x = acc0[0] * inv_c; v.y = acc0[1] * inv_c;
    v.z = acc0[2] * inv_c; v.w = acc0[3] * inv_c;
    *reinterpret_cast<float4*>(outB + (size_t)(c0 + 0) * HW) = v;
    v.x = acc1[0] * inv_c; v.y = acc1[1] * inv_c;
    v.z = acc1[2] * inv_c; v.w = acc1[3] * inv_c;
    *reinterpret_cast<float4*>(outB + (size_t)(c0 + 1) * HW) = v;
    v.x = acc2[0] * inv_c; v.y = acc2[1] * inv_c;
    v.z = acc2[2] * inv_c; v.w = acc2[3] * inv_c;
    *reinterpret_cast<float4*>(outB + (size_t)(c0 + 2) * HW) = v;
    v.x = acc3[0] * inv_c; v.y = acc3[1] * inv_c;
    v.z = acc3[2] * inv_c; v.w = acc3[3] * inv_c;
    *reinterpret_cast<float4*>(outB + (size_t)(c0 + 3) * HW) = v;
  }
}

extern "C" void kernel_launch(void* const* d_in, const int* in_sizes, int n_in,
                              void* d_out, int out_size, void* d_ws, size_t ws_size,
                              hipStream_t stream) {
  const float* first  = (const float*)d_in[0];
  const float* second = (const float*)d_in[1];
  float* out = (float*)d_out;

  corr_transpose_kernel<<<dim3(NWG), 256, 0, stream>>>(first, second, out);
}